// Round 3
// baseline (232.245 us; speedup 1.0000x reference)
//
#include <hip/hip_runtime.h>

// Sparsemax, last dim d=1024, 32768 rows, fp32.
// Persistent waves (2048 blocks x 4 waves = 8192 waves), each wave
// grid-strides 4 rows with an ENFORCED 2-deep register pipeline:
// next row's 4 dwordx4 loads are issued, then sched_barrier(0) pins
// them above the current row's solve (R2's version had no barrier and
// the compiler sank the loads -- VGPR_Count 32 proved the pipeline was
// dead). Stores are PLAIN (not nontemporal): the only kernels measured
// at >6 TB/s on this chip use cached stores; the nt path is suspect #1
// for the ~2.5 TB/s write ceiling seen in R0-R2.
// ZERO LDS: wave reductions via DPP (row_shr + row_bcast) on VALU;
// support counts via ballot+popcount on SALU. Newton iteration
//   t' = t + (sum(relu(z-t)) - 1)/#{z>t}
// from t0 = max-1 is monotone from below on the convex piecewise-linear
// objective and lands exactly on the root's linear segment (~4-6 iters).
// Divide via v_rcp_f32 (n is an exact small int; ~2^-22 rel err, and the
// final Newton step -> 0, so tau error ~1e-7 << 2e-3 tolerance).

#define ROW_D 1024

typedef float f4 __attribute__((ext_vector_type(4)));

template <int CTRL, int RMASK>
__device__ __forceinline__ float dpp_mv(float x) {
    return __builtin_bit_cast(float, __builtin_amdgcn_update_dpp(
        __builtin_bit_cast(int, x), __builtin_bit_cast(int, x),
        CTRL, RMASK, 0xf, false));
}

// Wave64 sum -> total lands in lane 63. row_shr:k folds each 16-lane row
// into its top lane; bcast15/31 fold rows.
__device__ __forceinline__ float dpp_sum_to63(float x) {
    x += dpp_mv<0x111, 0xf>(x);   // row_shr:1
    x += dpp_mv<0x112, 0xf>(x);   // row_shr:2
    x += dpp_mv<0x114, 0xf>(x);   // row_shr:4
    x += dpp_mv<0x118, 0xf>(x);   // row_shr:8
    x += dpp_mv<0x142, 0xa>(x);   // row_bcast15 -> rows 1,3
    x += dpp_mv<0x143, 0xc>(x);   // row_bcast31 -> rows 2,3
    return x;
}
__device__ __forceinline__ float dpp_max_to63(float x) {
    x = fmaxf(x, dpp_mv<0x111, 0xf>(x));
    x = fmaxf(x, dpp_mv<0x112, 0xf>(x));
    x = fmaxf(x, dpp_mv<0x114, 0xf>(x));
    x = fmaxf(x, dpp_mv<0x118, 0xf>(x));
    x = fmaxf(x, dpp_mv<0x142, 0xa>(x));
    x = fmaxf(x, dpp_mv<0x143, 0xc>(x));
    return x;
}
__device__ __forceinline__ float bcast63(float x) {
    return __builtin_bit_cast(float,
        __builtin_amdgcn_readlane(__builtin_bit_cast(int, x), 63));
}
__device__ __forceinline__ float fast_rcp(float x) {
    float r;
    asm("v_rcp_f32 %0, %1" : "=v"(r) : "v"(x));
    return r;
}

__device__ __forceinline__ void load_row(f4 (&v)[4], const float* __restrict__ z,
                                         int row, int lane) {
    const f4* __restrict__ p = reinterpret_cast<const f4*>(z + (size_t)row * ROW_D);
#pragma unroll
    for (int j = 0; j < 4; ++j) v[j] = p[lane + 64 * j];
}

__device__ __forceinline__ void solve_store(f4 (&v)[4], float* __restrict__ out,
                                            int row, int lane) {
    // Row max: pairwise tree in registers, then DPP wave-max.
    float mj[4];
#pragma unroll
    for (int j = 0; j < 4; ++j)
        mj[j] = fmaxf(fmaxf(v[j].x, v[j].y), fmaxf(v[j].z, v[j].w));
    float m = fmaxf(fmaxf(mj[0], mj[1]), fmaxf(mj[2], mj[3]));
    m = bcast63(dpp_max_to63(m));

    // Newton from below; wave-uniform everything, no divergence.
    float t = m - 1.0f;
#pragma unroll 1
    for (int it = 0; it < 16; ++it) {
        float sj[4];
        int n = 0;
#pragma unroll
        for (int j = 0; j < 4; ++j) {
            const float d0 = v[j].x - t, d1 = v[j].y - t;
            const float d2 = v[j].z - t, d3 = v[j].w - t;
            sj[j] = (fmaxf(d0, 0.0f) + fmaxf(d1, 0.0f)) +
                    (fmaxf(d2, 0.0f) + fmaxf(d3, 0.0f));
            n += __popcll(__ballot(d0 > 0.0f));
            n += __popcll(__ballot(d1 > 0.0f));
            n += __popcll(__ballot(d2 > 0.0f));
            n += __popcll(__ballot(d3 > 0.0f));
        }
        const float S = bcast63(dpp_sum_to63((sj[0] + sj[1]) + (sj[2] + sj[3])));
        // n >= 1 always (t stays strictly below max).
        const float step = (S - 1.0f) * fast_rcp((float)n);
        t += step;
        if (step <= 1e-6f) break;   // wave-uniform exit
    }

    // p = relu(z - tau); PLAIN stores (cached) -- nt path under test.
    f4* __restrict__ p = reinterpret_cast<f4*>(out + (size_t)row * ROW_D);
#pragma unroll
    for (int j = 0; j < 4; ++j) {
        f4 o;
        o.x = fmaxf(v[j].x - t, 0.0f);
        o.y = fmaxf(v[j].y - t, 0.0f);
        o.z = fmaxf(v[j].z - t, 0.0f);
        o.w = fmaxf(v[j].w - t, 0.0f);
        p[lane + 64 * j] = o;
    }
}

__global__ __launch_bounds__(256, 8) void sparsemax_kernel(
    const float* __restrict__ z, float* __restrict__ out, int nrows) {
    const int lane = (int)(threadIdx.x & 63u);
    int r = (int)(blockIdx.x << 2) + (int)(threadIdx.x >> 6);
    const int W = (int)(gridDim.x << 2);   // total waves = rows per stage
    if (r >= nrows) return;

    // Two register buffers, statically named. sched_barrier(0) forbids
    // the scheduler from sinking the prefetch loads below the solve
    // (the R2 failure mode). Counted s_waitcnt vmcnt(4) then lets the
    // prefetch stay in flight across the whole Newton phase.
    f4 A[4], B[4];
    load_row(A, z, r, lane);
    int rn = r + W;
    for (;;) {
        if (rn < nrows) load_row(B, z, rn, lane);   // prefetch next row
        __builtin_amdgcn_sched_barrier(0);          // pin loads above solve
        solve_store(A, out, r, lane);
        if (rn >= nrows) break;
        r = rn + W;
        if (r < nrows) load_row(A, z, r, lane);     // prefetch
        __builtin_amdgcn_sched_barrier(0);
        solve_store(B, out, rn, lane);
        if (r >= nrows) break;
        rn = r + W;
    }
}

extern "C" void kernel_launch(void* const* d_in, const int* in_sizes, int n_in,
                              void* d_out, int out_size, void* d_ws, size_t ws_size,
                              hipStream_t stream) {
    const float* z = (const float*)d_in[0];
    float* out = (float*)d_out;
    const int n = in_sizes[0];            // 8*4096*1024
    const int nrows = n / ROW_D;          // 32768
    // 2048 blocks x 4 waves = 8192 persistent waves (32/CU on 256 CUs);
    // each wave pipelines nrows/8192 = 4 rows.
    int blocks = 2048;
    const int max_blocks = (nrows + 3) >> 2;
    if (blocks > max_blocks) blocks = max_blocks;
    sparsemax_kernel<<<blocks, 256, 0, stream>>>(z, out, nrows);
}